// Round 20
// baseline (236.316 us; speedup 1.0000x reference)
//
#include <hip/hip_runtime.h>

typedef __attribute__((ext_vector_type(4))) float f32x4;
typedef __attribute__((ext_vector_type(8))) short bf16x8;
typedef __attribute__((ext_vector_type(4))) unsigned int u32x4;

__device__ __forceinline__ unsigned short f2bf(float f) {
    union { float f; unsigned int u; } x; x.f = f;
    unsigned int u = x.u;
    return (unsigned short)((u + 0x7FFFu + ((u >> 16) & 1u)) >> 16);
}
__device__ __forceinline__ float bf2f(unsigned short b) {
    union { unsigned int u; float f; } x; x.u = ((unsigned int)b) << 16;
    return x.f;
}
__device__ __forceinline__ float u2f(unsigned int u) {
    union { unsigned int u; float f; } x; x.u = u; return x.f;
}

// blocked layout (row r, ch k), 128-row blocks: ((r>>7)*8 + (k>>5))*4096 + (r&127)*32 + (k&31)
// LDS tiles: 16B-chunk XOR swizzle, chunk c of row r at c ^ ((r>>1)&3); staging pre-swizzles
// the per-lane GLOBAL source (LDS dest linear); reads use chunk lk ^ ((lrow>>1)&3).
// kv_t layout: [pixel][head][K ch 0-31 | V ch 0-31] bf16 (head-interleaved, 128B per head).

// ---------------- prep (merged): Wkv blocked bf16, Woff blocked bf16, Wcat=[Wq|Woff] fp32 ----------------
__global__ void prep_all(const float* __restrict__ Wk, const float* __restrict__ bk,
                         const float* __restrict__ Wv, const float* __restrict__ bv,
                         const float* __restrict__ Wq, const float* __restrict__ bq,
                         const float* __restrict__ Woff, const float* __restrict__ boff,
                         unsigned short* __restrict__ Wkv, float* __restrict__ bkv,
                         unsigned short* __restrict__ Woffp,
                         float* __restrict__ Wcat, float* __restrict__ bcat) {
    int i = blockIdx.x * 256 + threadIdx.x;   // grid 512*256 = 131072
    if (i < 512 * 256) {
        int n = i >> 8, k = i & 255;
        float v = (n < 256) ? Wk[i] : Wv[i - 65536];
        Wkv[((size_t)(n >> 7) * 8 + (k >> 5)) * 4096 + (n & 127) * 32 + (k & 31)] = f2bf(v);
    }
    if (i < 512) bkv[i] = (i < 256) ? bk[i] : bv[i - 256];
    if (i < 64 * 256) {
        int n = i >> 8, k = i & 255;
        Woffp[(size_t)(k >> 5) * 4096 + n * 32 + (k & 31)] = f2bf(Woff[i]);
    }
    if (i < 320 * 256) Wcat[i] = (i < 65536) ? Wq[i] : Woff[i - 65536];
    if (i < 320) bcat[i] = (i < 256) ? bq[i] : boff[i - 256];
}

// ---------------- transpose features [48][256][2816] -> bf16 blocked ----------------
__global__ __launch_bounds__(256) void transpose_feat(const float* __restrict__ src,
                                                      unsigned short* __restrict__ dst) {
    __shared__ float tile[32][33];
    int img = blockIdx.z;
    int p0 = blockIdx.x * 32;   // pixel
    int d0 = blockIdx.y * 32;   // channel
    int tx = threadIdx.x & 31, ty = threadIdx.x >> 5;
    const float* s = src + (size_t)img * 256 * 2816;
#pragma unroll
    for (int i = 0; i < 4; i++) tile[ty + 8 * i][tx] = s[(size_t)(d0 + ty + 8 * i) * 2816 + p0 + tx];
    __syncthreads();
    int m = img * 2816 + p0;
    unsigned short* o = dst + ((size_t)(m >> 7) * 8 + (d0 >> 5)) * 4096 + (m & 127) * 32;
#pragma unroll
    for (int i = 0; i < 4; i++) o[(ty + 8 * i) * 32 + tx] = f2bf(tile[tx][ty + 8 * i]);
}

// ---------------- kv+off projection: K+V paired, 40KB LDS (4 blocks/CU), full-line writes ----------------
// bn 0..3: 128 px x [K slab bn | V slab bn+4] -> kv_t heads 2bn,2bn+1 (256B/px contiguous)
// bn 4   : Foff[135168][64] fp32 = A @ Woff^T (no bias; dummy V operand)
// B staged in QUARTERS (2 kt x [64K|64V] rows = 16KB), restaged 3x mid-loop (barrier pairs).
// A ring: 3 slots x 8KB, depth-2 prefetch. LDS 40KB.
__global__ __launch_bounds__(256) void gemm_kv2(
    const unsigned short* __restrict__ A,
    const unsigned short* __restrict__ Wkv,
    const unsigned short* __restrict__ Woffp,
    const float* __restrict__ bias,
    unsigned short* __restrict__ C,
    float* __restrict__ Foff) {
    __shared__ __align__(16) unsigned short Bl[8192];     // 16KB: [kt&1][64K r|64V r][32c] (swizzled)
    __shared__ __align__(16) unsigned short Ar[3][4096];  // ring: [slot][128r][32c] (swizzled)

    const int tid = threadIdx.x, lane = tid & 63, w = tid >> 6;
    const int lrow = lane & 15, lk = lane >> 4;
    const int lsw = (lane >> 2) * 32 + (((lane & 3) ^ ((lane >> 3) & 3)) * 8);
    const int ckx = ((lrow >> 1) & 3);    // read-side chunk xor
    const int bid = blockIdx.x;
    const int wgid = (bid & 7) * 660 + (bid >> 3);   // XCD swizzle (5280 = 8*660)
    const int chunk = wgid / 5, bn = wgid % 5;       // chunk: m-block 0..1055, bn: 0..4

    const unsigned short* A0 = A + (size_t)chunk * 32768;
    const unsigned short* BbK = (bn < 4)
        ? Wkv + (size_t)(bn >> 1) * 32768 + (bn & 1) * 2048
        : Woffp;
    const unsigned short* BbV = (bn < 4)
        ? Wkv + (size_t)((bn + 4) >> 1) * 32768 + ((bn + 4) & 1) * 2048
        : Woffp;                                     // dummy (uniform load counts)
    const int wof = w * 1024;   // wave-private 32-row region (shorts) within a slot

    // stage B quarter Q (kt = 2Q, 2Q+1): wave w -> kt_local w>>1, KV w&1, 4 x 1KB
#define STAGE_BQ(Q)                                                                          \
    {                                                                                        \
        const unsigned short* src = ((w & 1) ? BbV : BbK) + ((Q) * 2 + (w >> 1)) * 4096;     \
        _Pragma("unroll")                                                                    \
        for (int i = 0; i < 4; ++i) {                                                        \
            __builtin_amdgcn_global_load_lds(                                                \
                (const __attribute__((address_space(1))) unsigned int*)(src + i * 512 + lsw),\
                (__attribute__((address_space(3))) unsigned int*)&Bl[(w >> 1) * 4096 + (w & 1) * 2048 + i * 512], 16, 0, 0); \
        }                                                                                    \
    }

#define STAGE_STEP(S)                                                                        \
    {                                                                                        \
        __builtin_amdgcn_global_load_lds(                                                    \
            (const __attribute__((address_space(1))) unsigned int*)(A0 + (S) * 4096 + wof + lsw),        \
            (__attribute__((address_space(3))) unsigned int*)&Ar[(S) % 3][wof], 16, 0, 0);   \
        __builtin_amdgcn_global_load_lds(                                                    \
            (const __attribute__((address_space(1))) unsigned int*)(A0 + (S) * 4096 + wof + 512 + lsw),  \
            (__attribute__((address_space(3))) unsigned int*)&Ar[(S) % 3][wof + 512], 16, 0, 0);         \
    }

    STAGE_BQ(0)
    STAGE_STEP(0) STAGE_STEP(1)
    __syncthreads();   // drains: B quarter0 + A0,A1 resident

    f32x4 acc[2][8] = {};   // [i][j]; j 0-3 = K slab, j 4-7 = V slab

    // COMP: (barriers handle A/B-landing sync) ds_read frags -> drain own ds_reads ->
    // stage A(S+2) -> 16 MFMAs. kt-local-in-quarter = S&1.
#define COMP_STEP(S)                                                                         \
    {                                                                                        \
        bf16x8 bfr[8], af[2];                                                                \
        _Pragma("unroll") for (int j = 0; j < 4; ++j)                                        \
            bfr[j] = *(const bf16x8*)&Bl[((S) & 1) * 4096 + (j * 16 + lrow) * 32 + (lk ^ ckx) * 8];          \
        _Pragma("unroll") for (int j = 0; j < 4; ++j)                                        \
            bfr[4 + j] = *(const bf16x8*)&Bl[((S) & 1) * 4096 + 2048 + (j * 16 + lrow) * 32 + (lk ^ ckx) * 8]; \
        _Pragma("unroll") for (int i = 0; i < 2; ++i)                                        \
            af[i] = *(const bf16x8*)&Ar[(S) % 3][wof + i * 512 + lrow * 32 + (lk ^ ckx) * 8];\
        if ((S) + 2 < 8) {                                                                   \
            asm volatile("s_waitcnt lgkmcnt(0)" ::: "memory");                               \
            STAGE_STEP((S) + 2)                                                              \
        }                                                                                    \
        _Pragma("unroll") for (int i = 0; i < 2; ++i)                                        \
            _Pragma("unroll") for (int j = 0; j < 8; ++j)                                    \
                acc[i][j] = __builtin_amdgcn_mfma_f32_16x16x32_bf16(af[i], bfr[j], acc[i][j], 0, 0, 0); \
    }

    COMP_STEP(0) COMP_STEP(1)
    __syncthreads(); STAGE_BQ(1) __syncthreads();
    COMP_STEP(2) COMP_STEP(3)
    __syncthreads(); STAGE_BQ(2) __syncthreads();
    COMP_STEP(4) COMP_STEP(5)
    __syncthreads(); STAGE_BQ(3) __syncthreads();
    COMP_STEP(6) COMP_STEP(7)
#undef COMP_STEP
#undef STAGE_STEP
#undef STAGE_BQ

    if (bn < 4) {
        // epilogue: two 64-px team passes through Bl (16KB): acc -> Cl[64px][128cols]
        // -> 256B contiguous full-line stores. Wave w owns px w*32..w*32+31; team = w>>1.
        unsigned short* Cl = &Bl[0];
#pragma unroll
        for (int pteam = 0; pteam < 2; ++pteam) {
            __syncthreads();
            if ((w >> 1) == pteam) {
#pragma unroll
                for (int j = 0; j < 8; ++j) {
                    float bs = (j < 4) ? bias[bn * 64 + j * 16 + lrow]
                                       : bias[(bn + 4) * 64 + (j - 4) * 16 + lrow];
#pragma unroll
                    for (int i = 0; i < 2; ++i)
#pragma unroll
                        for (int jj = 0; jj < 4; ++jj)
                            Cl[((w & 1) * 32 + i * 16 + lk * 4 + jj) * 128 + j * 16 + lrow] =
                                f2bf(acc[i][j][jj] + bs);
                }
            }
            __syncthreads();
            // dst d-chunk (16/px): [h0K(0-3) h0V(4-7) h1K(8-11) h1V(12-15)]
            // src s in Cl: [K0 K1 V0 V1]
#pragma unroll
            for (int it = 0; it < 4; ++it) {
                int idx = it * 256 + tid;
                int px = idx >> 4, d = idx & 15;
                int s = (d < 4) ? d : (d < 8) ? d + 4 : (d < 12) ? d - 4 : d;
                *(f32x4*)(C + (size_t)(chunk * 128 + pteam * 64 + px) * 512 + bn * 128 + d * 8) =
                    *(const f32x4*)&Cl[px * 128 + s * 8];
            }
        }
    } else {
        // Foff epilogue: fp32 direct stores (no bias); only K-slab accs meaningful
#pragma unroll
        for (int i = 0; i < 2; ++i)
#pragma unroll
            for (int j = 0; j < 4; ++j)
#pragma unroll
                for (int jj = 0; jj < 4; ++jj) {
                    int m = chunk * 128 + w * 32 + i * 16 + lk * 4 + jj;
                    Foff[(size_t)m * 64 + j * 16 + lrow] = acc[i][j][jj];
                }
    }
}

// ---------------- split-bf16 MFMA GEMM (fp32 A/B in): C = A@B^T + bias ----------------
template <bool SPLIT, bool C_BF16>
__global__ __launch_bounds__(256) void gemm_bf16(
    const float* __restrict__ A, long long aBatch,
    const float* __restrict__ B, const float* __restrict__ bias,
    void* __restrict__ Cv, long long cBatch,
    int M, int N, int K, int lda) {
    __shared__ __align__(16) unsigned short Ah[64][40];
    __shared__ __align__(16) unsigned short Bh[64][40];
    __shared__ __align__(16) unsigned short Al[(SPLIT ? 64 : 1)][40];
    __shared__ __align__(16) unsigned short Bl[(SPLIT ? 64 : 1)][40];

    const int tid = threadIdx.x;
    const int m0 = blockIdx.x * 64, n0 = blockIdx.y * 64;
    const int batch = blockIdx.z;
    const float* Ab = A + (size_t)batch * aBatch;
    const int lane = tid & 63, wave = tid >> 6;
    const int wr = wave & 1, wc = wave >> 1;
    const int lrow = lane & 15, lk = lane >> 4;

    f32x4 acc[2][2] = {};

    for (int kt = 0; kt < K; kt += 32) {
        if (kt) __syncthreads();
        {
            int c4 = (tid & 7) * 4;
#pragma unroll
            for (int rep = 0; rep < 2; rep++) {
                int r = (tid >> 3) + rep * 32;
                int m = m0 + r; if (m >= M) m = M - 1;
                f32x4 v = *(const f32x4*)(Ab + (size_t)m * lda + kt + c4);
#pragma unroll
                for (int q = 0; q < 4; q++) {
                    unsigned short h = f2bf(v[q]);
                    Ah[r][c4 + q] = h;
                    if (SPLIT) Al[r][c4 + q] = f2bf(v[q] - bf2f(h));
                }
            }
        }
        {
            int c4 = (tid & 7) * 4;
#pragma unroll
            for (int rep = 0; rep < 2; rep++) {
                int r = (tid >> 3) + rep * 32;
                f32x4 v = *(const f32x4*)(B + (size_t)(n0 + r) * K + kt + c4);
#pragma unroll
                for (int q = 0; q < 4; q++) {
                    unsigned short h = f2bf(v[q]);
                    Bh[r][c4 + q] = h;
                    if (SPLIT) Bl[r][c4 + q] = f2bf(v[q] - bf2f(h));
                }
            }
        }
        __syncthreads();

        bf16x8 a_h[2], b_h[2], a_l[2], b_l[2];
#pragma unroll
        for (int i = 0; i < 2; i++) {
            a_h[i] = *(const bf16x8*)&Ah[wr * 32 + i * 16 + lrow][lk * 8];
            b_h[i] = *(const bf16x8*)&Bh[wc * 32 + i * 16 + lrow][lk * 8];
            if (SPLIT) {
                a_l[i] = *(const bf16x8*)&Al[wr * 32 + i * 16 + lrow][lk * 8];
                b_l[i] = *(const bf16x8*)&Bl[wc * 32 + i * 16 + lrow][lk * 8];
            }
        }
#pragma unroll
        for (int i = 0; i < 2; i++)
#pragma unroll
            for (int j = 0; j < 2; j++) {
                acc[i][j] = __builtin_amdgcn_mfma_f32_16x16x32_bf16(a_h[i], b_h[j], acc[i][j], 0, 0, 0);
                if (SPLIT) {
                    acc[i][j] = __builtin_amdgcn_mfma_f32_16x16x32_bf16(a_h[i], b_l[j], acc[i][j], 0, 0, 0);
                    acc[i][j] = __builtin_amdgcn_mfma_f32_16x16x32_bf16(a_l[i], b_h[j], acc[i][j], 0, 0, 0);
                }
            }
    }

#pragma unroll
    for (int i = 0; i < 2; i++)
#pragma unroll
        for (int j = 0; j < 2; j++) {
            int n = n0 + wc * 32 + j * 16 + lrow;
            float bs = bias[n];
#pragma unroll
            for (int jj = 0; jj < 4; jj++) {
                int m = m0 + wr * 32 + i * 16 + lk * 4 + jj;
                if (m < M) {
                    float val = acc[i][j][jj] + bs;
                    if (C_BF16)
                        ((unsigned short*)Cv)[(size_t)batch * cBatch + (size_t)m * N + n] = f2bf(val);
                    else
                        ((float*)Cv)[(size_t)batch * cBatch + (size_t)m * N + n] = val;
                }
            }
        }
}

// ---------------- fused deformable attention (projection + offsets fused in) ----------------
__global__ __launch_bounds__(512) void attn_kernel(
    const float* __restrict__ qcat, const float* __restrict__ points,
    const float* __restrict__ camM, const float* __restrict__ camb,
    const float* __restrict__ Foff, const unsigned short* __restrict__ kv_t,
    float* __restrict__ S) {
    int bk = blockIdx.x;            // b*900 + k
    int b = bk / 900, k = bk % 900;
    int h = threadIdx.x >> 6;       // wave = head
    int lane = threadIdx.x & 63;

    __shared__ __align__(16) float        ldsW[8][24][4];
    __shared__ __align__(16) unsigned int ldsI[8][24][4];
    __shared__ float ldsL[8][24];

    if (lane < 24) {
        int cam = lane >> 2, p = lane & 3;
        float pt0 = points[(size_t)bk * 3 + 0];
        float pt1 = points[(size_t)bk * 3 + 1];
        float pt2 = points[(size_t)bk * 3 + 2];
        const float* M = camM + cam * 6;
        float s0 = M[0] * pt0 + M[1] * pt1 + M[2] * pt2 + camb[cam * 2 + 0];
        float s1 = M[3] * pt0 + M[4] * pt1 + M[5] * pt2 + camb[cam * 2 + 1];
        float px0 = (1.f / (1.f + expf(-s0))) * 32.f;
        float px1 = (1.f / (1.f + expf(-s1))) * 88.f;
        {
            float gxb = 2.f * px0 / 32.f - 1.f, gyb = 2.f * px1 / 88.f - 1.f;
            float ixb = (gxb + 1.f) * 0.5f * 87.f;
            float iyb = (gyb + 1.f) * 0.5f * 31.f;
            float xb0 = floorf(ixb), yb0 = floorf(iyb), xb1 = xb0 + 1.f, yb1 = yb0 + 1.f;
            float wxb1 = ixb - xb0, wxb0 = xb1 - ixb, wyb1 = iyb - yb0, wyb0 = yb1 - iyb;
            float mb00 = (xb0 >= 0.f && xb0 <= 87.f && yb0 >= 0.f && yb0 <= 31.f) ? 1.f : 0.f;
            float mb01 = (xb1 >= 0.f && xb1 <= 87.f && yb0 >= 0.f && yb0 <= 31.f) ? 1.f : 0.f;
            float mb10 = (xb0 >= 0.f && xb0 <= 87.f && yb1 >= 0.f && yb1 <= 31.f) ? 1.f : 0.f;
            float mb11 = (xb1 >= 0.f && xb1 <= 87.f && yb1 >= 0.f && yb1 <= 31.f) ? 1.f : 0.f;
            float wb00 = wxb0 * wyb0 * mb00, wb01 = wxb1 * wyb0 * mb01;
            float wb10 = wxb0 * wyb1 * mb10, wb11 = wxb1 * wyb1 * mb11;
            int xib0 = (int)fminf(fmaxf(xb0, 0.f), 87.f);
            int xib1 = (int)fminf(fmaxf(xb1, 0.f), 87.f);
            int yib0 = (int)fminf(fmaxf(yb0, 0.f), 31.f);
            int yib1 = (int)fminf(fmaxf(yb1, 0.f), 31.f);
            size_t base = (size_t)(cam * 8 + b) * 2816;
            const float* f00 = Foff + (base + yib0 * 88 + xib0) * 64;
            const float* f01 = Foff + (base + yib0 * 88 + xib1) * 64;
            const float* f10 = Foff + (base + yib1 * 88 + xib0) * 64;
            const float* f11 = Foff + (base + yib1 * 88 + xib1) * 64;
            int j0 = (h * 4 + p) * 2;
            float o0 = qcat[(size_t)bk * 320 + 256 + j0]
                     + wb00 * f00[j0] + wb01 * f01[j0] + wb10 * f10[j0] + wb11 * f11[j0];
            float o1 = qcat[(size_t)bk * 320 + 256 + j0 + 1]
                     + wb00 * f00[j0 + 1] + wb01 * f01[j0 + 1] + wb10 * f10[j0 + 1] + wb11 * f11[j0 + 1];
            float pc0 = px0 + o0 * (1.f / 32.f);
            float pc1 = px1 + o1 * (1.f / 88.f);
            float gx = 2.f * (pc0 * (1.f / 32.f)) - 1.f;
            float gy = 2.f * (pc1 * (1.f / 88.f)) - 1.f;
            float ix = (gx + 1.f) * 0.5f * 87.f;
            float iy = (gy + 1.f) * 0.5f * 31.f;
            float x0 = floorf(ix), y0 = floorf(iy), x1 = x0 + 1.f, y1 = y0 + 1.f;
            float wx1 = ix - x0, wx0 = x1 - ix, wy1 = iy - y0, wy0 = y1 - iy;
            float m00 = (x0 >= 0.f && x0 <= 87.f && y0 >= 0.f && y0 <= 31.f) ? 1.f : 0.f;
            float m01 = (x1 >= 0.f && x1 <= 87.f && y0 >= 0.f && y0 <= 31.f) ? 1.f : 0.f;
            float m10 = (x0 >= 0.f && x0 <= 87.f && y1 >= 0.f && y1 <= 31.f) ? 1.f : 0.f;
            float m11 = (x1 >= 0.f && x1 <= 87.f && y1 >= 0.f && y1 <= 31.f) ? 1.f : 0.f;
            int xi0 = (int)fminf(fmaxf(x0, 0.f), 87.f);
            int xi1 = (int)fminf(fmaxf(x1, 0.f), 87.f);
            int yi0 = (int)fminf(fmaxf(y0, 0.f), 31.f);
            int yi1 = (int)fminf(fmaxf(y1, 0.f), 31.f);
            unsigned int img = (unsigned int)(cam * 8 + b) * 2816u;
            ldsW[h][lane][0] = wx0 * wy0 * m00;
            ldsW[h][lane][1] = wx1 * wy0 * m01;
            ldsW[h][lane][2] = wx0 * wy1 * m10;
            ldsW[h][lane][3] = wx1 * wy1 * m11;
            ldsI[h][lane][0] = (img + yi0 * 88 + xi0) * 1024u;
            ldsI[h][lane][1] = (img + yi0 * 88 + xi1) * 1024u;
            ldsI[h][lane][2] = (img + yi1 * 88 + xi0) * 1024u;
            ldsI[h][lane][3] = (img + yi1 * 88 + xi1) * 1024u;
        }
    }
    __syncthreads();

    const int p8 = lane >> 3, dlane = lane & 7;
    const int chB = h * 128 + dlane * 16;    // byte offset within pixel row
    const char* kvb = (const char*)kv_t;

    f32x4 qa = *(const f32x4*)(qcat + (size_t)bk * 320 + h * 32 + (dlane & 3) * 8);
    f32x4 qb = *(const f32x4*)(qcat + (size_t)bk * 320 + h * 32 + (dlane & 3) * 8 + 4);

    float vr[3][8];
    const float inv_sqrt = 0.17677669529663687f;
#pragma unroll
    for (int it = 0; it < 3; ++it) {
        int l = it * 8 + p8;
        f32x4 w = *(const f32x4*)ldsW[h][l];
        unsigned int i0 = ldsI[h][l][0], i1 = ldsI[h][l][1];
        unsigned int i2 = ldsI[h][l][2], i3 = ldsI[h][l][3];
        u32x4 u0 = *(const u32x4*)(kvb + i0 + chB);
        u32x4 u1 = *(const u32x4*)(kvb + i1 + chB);
        u32x4 u2 = *(const u32x4*)(kvb + i2 + chB);
        u32x4 u3 = *(const u32x4*)(kvb + i3 + chB);
#pragma unroll
        for (int q = 0; q < 4; ++q) {
            vr[it][2 * q] = w[0] * u2f(u0[q] << 16) + w[1] * u2f(u1[q] << 16)
                          + w[2] * u2f(u2[q] << 16) + w[3] * u2f(u3[q] << 16);
            vr[it][2 * q + 1] = w[0] * u2f(u0[q] & 0xFFFF0000u) + w[1] * u2f(u1[q] & 0xFFFF0000u)
                              + w[2] * u2f(u2[q] & 0xFFFF0000u) + w[3] * u2f(u3[q] & 0xFFFF0000u);
        }
        float t = qa[0] * vr[it][0] + qa[1] * vr[it][1] + qa[2] * vr[it][2] + qa[3] * vr[it][3]
                + qb[0] * vr[it][4] + qb[1] * vr[it][5] + qb[2] * vr[it][6] + qb[3] * vr[it][7];
        t += __shfl_xor(t, 1);
        t += __shfl_xor(t, 2);
        if (dlane == 0) ldsL[h][l] = t * inv_sqrt;
    }
    __syncthreads();

    float mx = -1e30f;
#pragma unroll
    for (int l = 0; l < 24; l++) mx = fmaxf(mx, ldsL[h][l]);
    float ssum = 0.f;
    float at3[3];
#pragma unroll
    for (int l = 0; l < 24; l++) {
        float e = __expf(ldsL[h][l] - mx);
        ssum += e;
        if ((l & 7) == p8) at3[l >> 3] = e;
    }
    float inv = 1.f / ssum;

    float o[8];
#pragma unroll
    for (int j = 0; j < 8; ++j)
        o[j] = at3[0] * vr[0][j] + at3[1] * vr[1][j] + at3[2] * vr[2][j];
#pragma unroll
    for (int j = 0; j < 8; ++j) {
        o[j] += __shfl_xor(o[j], 8);
        o[j] += __shfl_xor(o[j], 16);
        o[j] += __shfl_xor(o[j], 32);
    }
    if (p8 == 0 && dlane >= 4) {
        int d0 = (dlane - 4) * 8;
        f32x4 v0, v1;
        v0[0] = o[0] * inv; v0[1] = o[1] * inv; v0[2] = o[2] * inv; v0[3] = o[3] * inv;
        v1[0] = o[4] * inv; v1[1] = o[5] * inv; v1[2] = o[6] * inv; v1[3] = o[7] * inv;
        float* dst = &S[(size_t)b * 230400 + (size_t)h * 28800 + k * 32 + d0];
        *(f32x4*)dst = v0;
        *(f32x4*)(dst + 4) = v1;
    }
}

extern "C" void kernel_launch(void* const* d_in, const int* in_sizes, int n_in,
                              void* d_out, int out_size, void* d_ws, size_t ws_size,
                              hipStream_t stream) {
    const float* query    = (const float*)d_in[0];
    const float* points   = (const float*)d_in[1];
    const float* features = (const float*)d_in[2];
    const float* camM     = (const float*)d_in[3];
    const float* camb     = (const float*)d_in[4];
    const float* W_off    = (const float*)d_in[5];
    const float* b_off    = (const float*)d_in[6];
    const float* W_q      = (const float*)d_in[7];
    const float* b_q      = (const float*)d_in[8];
    const float* W_k      = (const float*)d_in[9];
    const float* b_k      = (const float*)d_in[10];
    const float* W_v      = (const float*)d_in[11];
    const float* b_v      = (const float*)d_in[12];
    const float* W_o      = (const float*)d_in[13];
    const float* b_o      = (const float*)d_in[14];

    char* ws = (char*)d_ws;
    unsigned short* feat_t = (unsigned short*)ws; ws += 69206016;   // blocked [1056][8][128][32] bf16
    unsigned short* kv_t   = (unsigned short*)ws; ws += 138412032;  // [135168][8 heads][64] bf16
    float* Foff   = (float*)ws; ws += 34603008;                     // [135168][64]
    float* qcat   = (float*)ws; ws += 9216000;                      // [7200][320] = [q_proj | qWoff]
    float* S      = (float*)ws; ws += 7372800;                      // [8][230400] scrambled
    unsigned short* Wkv = (unsigned short*)ws; ws += 524288;        // blocked [4][8][128][32] bf16
    float* bkv    = (float*)ws; ws += 2048;                         // [512]
    unsigned short* Woffp = (unsigned short*)ws; ws += 65536;       // blocked [8 kt][4096] bf16
    float* Wcat   = (float*)ws; ws += 327680;                       // [320][256] fp32
    float* bcat   = (float*)ws; ws += 1280;                         // [320]

    prep_all<<<512, 256, 0, stream>>>(W_k, b_k, W_v, b_v, W_q, b_q, W_off, b_off,
                                      Wkv, bkv, Woffp, Wcat, bcat);
    transpose_feat<<<dim3(88, 8, 48), 256, 0, stream>>>(features, feat_t);
    // kv_t (bn 0-3, K+V paired full-line stores) + Foff (bn 4): 40KB, 4 blocks/CU
    gemm_kv2<<<5280, 256, 0, stream>>>(feat_t, Wkv, Woffp, bkv, kv_t, Foff);
    // qcat = query @ [W_q|W_off]^T + [b_q|b_off] : [7200 x 320]
    gemm_bf16<true, false><<<dim3(113, 5, 1), 256, 0, stream>>>(
        query, 0, Wcat, bcat, qcat, 0, 7200, 320, 256, 256);
    // attention (projection + offset sampling fused in)
    attn_kernel<<<7200, 512, 0, stream>>>(qcat, points, camM, camb, Foff, kv_t, S);
    // out = S @ W_o^T + b_o : [7200 x 256]
    gemm_bf16<true, false><<<dim3(113, 4, 1), 256, 0, stream>>>(
        S, 0, W_o, b_o, d_out, 0, 7200, 256, 256, 256);
}

// Round 21
// 234.049 us; speedup vs baseline: 1.0097x; 1.0097x over previous
//
#include <hip/hip_runtime.h>

typedef __attribute__((ext_vector_type(4))) float f32x4;
typedef __attribute__((ext_vector_type(8))) short bf16x8;
typedef __attribute__((ext_vector_type(4))) unsigned int u32x4;

__device__ __forceinline__ unsigned short f2bf(float f) {
    union { float f; unsigned int u; } x; x.f = f;
    unsigned int u = x.u;
    return (unsigned short)((u + 0x7FFFu + ((u >> 16) & 1u)) >> 16);
}
__device__ __forceinline__ float bf2f(unsigned short b) {
    union { unsigned int u; float f; } x; x.u = ((unsigned int)b) << 16;
    return x.f;
}
__device__ __forceinline__ float u2f(unsigned int u) {
    union { unsigned int u; float f; } x; x.u = u; return x.f;
}

// blocked layout (row r, ch k), 128-row blocks: ((r>>7)*8 + (k>>5))*4096 + (r&127)*32 + (k&31)
// LDS tiles: 16B-chunk XOR swizzle, chunk c of row r at c ^ ((r>>1)&3); staging pre-swizzles
// the per-lane GLOBAL source (LDS dest linear); reads use chunk lk ^ ((lrow>>1)&3).
// kv_t layout: [pixel][head][K ch 0-31 | V ch 0-31] bf16 (head-interleaved, 128B per head).

// ---------------- prep (merged): Wkv blocked bf16, Woff blocked bf16, Wcat=[Wq|Woff] fp32 ----------------
__global__ void prep_all(const float* __restrict__ Wk, const float* __restrict__ bk,
                         const float* __restrict__ Wv, const float* __restrict__ bv,
                         const float* __restrict__ Wq, const float* __restrict__ bq,
                         const float* __restrict__ Woff, const float* __restrict__ boff,
                         unsigned short* __restrict__ Wkv, float* __restrict__ bkv,
                         unsigned short* __restrict__ Woffp,
                         float* __restrict__ Wcat, float* __restrict__ bcat) {
    int i = blockIdx.x * 256 + threadIdx.x;   // grid 512*256 = 131072
    if (i < 512 * 256) {
        int n = i >> 8, k = i & 255;
        float v = (n < 256) ? Wk[i] : Wv[i - 65536];
        Wkv[((size_t)(n >> 7) * 8 + (k >> 5)) * 4096 + (n & 127) * 32 + (k & 31)] = f2bf(v);
    }
    if (i < 512) bkv[i] = (i < 256) ? bk[i] : bv[i - 256];
    if (i < 64 * 256) {
        int n = i >> 8, k = i & 255;
        Woffp[(size_t)(k >> 5) * 4096 + n * 32 + (k & 31)] = f2bf(Woff[i]);
    }
    if (i < 320 * 256) Wcat[i] = (i < 65536) ? Wq[i] : Woff[i - 65536];
    if (i < 320) bcat[i] = (i < 256) ? bq[i] : boff[i - 256];
}

// ---------------- transpose features [48][256][2816] -> bf16 blocked ----------------
__global__ __launch_bounds__(256) void transpose_feat(const float* __restrict__ src,
                                                      unsigned short* __restrict__ dst) {
    __shared__ float tile[32][33];
    int img = blockIdx.z;
    int p0 = blockIdx.x * 32;   // pixel
    int d0 = blockIdx.y * 32;   // channel
    int tx = threadIdx.x & 31, ty = threadIdx.x >> 5;
    const float* s = src + (size_t)img * 256 * 2816;
#pragma unroll
    for (int i = 0; i < 4; i++) tile[ty + 8 * i][tx] = s[(size_t)(d0 + ty + 8 * i) * 2816 + p0 + tx];
    __syncthreads();
    int m = img * 2816 + p0;
    unsigned short* o = dst + ((size_t)(m >> 7) * 8 + (d0 >> 5)) * 4096 + (m & 127) * 32;
#pragma unroll
    for (int i = 0; i < 4; i++) o[(ty + 8 * i) * 32 + tx] = f2bf(tile[tx][ty + 8 * i]);
}

// ---------------- kv+off projection: K+V paired cols (full-line writes), counted-vmcnt ----------------
// bn' 0..3: block computes 128 px x 128 cols = K-slab bn' (64) + V-slab bn'+4 (64)
//           = heads 2bn',2bn'+1 complete [K|V] -> 256B contiguous full-line stores.
// bn' 4   : Foff[135168][64] fp32 = A @ Woff^T (no bias; dummy V operand for uniform code).
// Block = 128 px; 4 waves, wave-private A staging. B half (32KB, kt0-3) staged, re-staged
// mid-loop. A ring: 3 slots x 8KB, depth-2, per-wave s_waitcnt vmcnt(N). LDS 56KB.
__global__ __launch_bounds__(256) void gemm_kv2(
    const unsigned short* __restrict__ A,
    const unsigned short* __restrict__ Wkv,
    const unsigned short* __restrict__ Woffp,
    const float* __restrict__ bias,
    unsigned short* __restrict__ C,
    float* __restrict__ Foff) {
    __shared__ __align__(16) unsigned short Bl[16384];    // 32KB: [kt-local][64K r|64V r][32c] (swizzled)
    __shared__ __align__(16) unsigned short Ar[3][4096];  // ring: [slot][128r][32c] (swizzled)

    const int tid = threadIdx.x, lane = tid & 63, w = tid >> 6;
    const int lrow = lane & 15, lk = lane >> 4;
    const int lsw = (lane >> 2) * 32 + (((lane & 3) ^ ((lane >> 3) & 3)) * 8);
    const int ckx = ((lrow >> 1) & 3);    // read-side chunk xor
    const int bid = blockIdx.x;
    const int wgid = (bid & 7) * 660 + (bid >> 3);   // XCD swizzle (5280 = 8*660)
    const int chunk = wgid / 5, bn = wgid % 5;       // chunk: m-block 0..1055, bn: 0..4

    const unsigned short* A0 = A + (size_t)chunk * 32768;
    const unsigned short* BbK = (bn < 4)
        ? Wkv + (size_t)(bn >> 1) * 32768 + (bn & 1) * 2048
        : Woffp;
    const unsigned short* BbV = (bn < 4)
        ? Wkv + (size_t)((bn + 4) >> 1) * 32768 + ((bn + 4) & 1) * 2048
        : Woffp;                                     // dummy (keeps load counts uniform)
    const int wof = w * 1024;   // wave-private 32-row region (shorts) within a slot

    // stage B half (32KB): wave w stages kt-local w: 4x1KB K rows + 4x1KB V rows
#define STAGE_B(HALF)                                                                        \
    {                                                                                        \
        _Pragma("unroll")                                                                    \
        for (int i = 0; i < 4; ++i) {                                                        \
            __builtin_amdgcn_global_load_lds(                                                \
                (const __attribute__((address_space(1))) unsigned int*)(BbK + ((HALF) * 4 + w) * 4096 + i * 512 + lsw), \
                (__attribute__((address_space(3))) unsigned int*)&Bl[w * 4096 + i * 512], 16, 0, 0);                    \
        }                                                                                    \
        _Pragma("unroll")                                                                    \
        for (int i = 0; i < 4; ++i) {                                                        \
            __builtin_amdgcn_global_load_lds(                                                \
                (const __attribute__((address_space(1))) unsigned int*)(BbV + ((HALF) * 4 + w) * 4096 + i * 512 + lsw), \
                (__attribute__((address_space(3))) unsigned int*)&Bl[w * 4096 + 2048 + i * 512], 16, 0, 0);             \
        }                                                                                    \
    }

#define STAGE_STEP(S)                                                                        \
    {                                                                                        \
        __builtin_amdgcn_global_load_lds(                                                    \
            (const __attribute__((address_space(1))) unsigned int*)(A0 + (S) * 4096 + wof + lsw),        \
            (__attribute__((address_space(3))) unsigned int*)&Ar[(S) % 3][wof], 16, 0, 0);   \
        __builtin_amdgcn_global_load_lds(                                                    \
            (const __attribute__((address_space(1))) unsigned int*)(A0 + (S) * 4096 + wof + 512 + lsw),  \
            (__attribute__((address_space(3))) unsigned int*)&Ar[(S) % 3][wof + 512], 16, 0, 0);         \
    }

    STAGE_B(0)
    STAGE_STEP(0) STAGE_STEP(1)
    __syncthreads();   // drains: B half0 + A0,A1 resident

    f32x4 acc[2][8] = {};   // [i][j]; j 0-3 = K slab, j 4-7 = V slab

    // COMP: wait A(S) -> ds_read frags -> drain own ds_reads -> stage A(S+2) -> 16 MFMAs
#define COMP_STEP(S, NW)                                                                     \
    {                                                                                        \
        asm volatile("s_waitcnt vmcnt(%0)" :: "i"(NW) : "memory");                           \
        bf16x8 bfr[8], af[2];                                                                \
        _Pragma("unroll") for (int j = 0; j < 4; ++j)                                        \
            bfr[j] = *(const bf16x8*)&Bl[((S) & 3) * 4096 + (j * 16 + lrow) * 32 + (lk ^ ckx) * 8];          \
        _Pragma("unroll") for (int j = 0; j < 4; ++j)                                        \
            bfr[4 + j] = *(const bf16x8*)&Bl[((S) & 3) * 4096 + 2048 + (j * 16 + lrow) * 32 + (lk ^ ckx) * 8]; \
        _Pragma("unroll") for (int i = 0; i < 2; ++i)                                        \
            af[i] = *(const bf16x8*)&Ar[(S) % 3][wof + i * 512 + lrow * 32 + (lk ^ ckx) * 8];\
        if ((S) + 2 < 8) {                                                                   \
            asm volatile("s_waitcnt lgkmcnt(0)" ::: "memory");                               \
            STAGE_STEP((S) + 2)                                                              \
        }                                                                                    \
        _Pragma("unroll") for (int i = 0; i < 2; ++i)                                        \
            _Pragma("unroll") for (int j = 0; j < 8; ++j)                                    \
                acc[i][j] = __builtin_amdgcn_mfma_f32_16x16x32_bf16(af[i], bfr[j], acc[i][j], 0, 0, 0); \
    }

    COMP_STEP(0, 4) COMP_STEP(1, 2) COMP_STEP(2, 2) COMP_STEP(3, 2)
    __syncthreads();          // all waves done reading B half0 (drains A4,A5 too)
    STAGE_B(1)
    __syncthreads();          // B half1 resident
    COMP_STEP(4, 4) COMP_STEP(5, 2) COMP_STEP(6, 2) COMP_STEP(7, 0)
#undef COMP_STEP
#undef STAGE_STEP
#undef STAGE_B

    if (bn < 4) {
        // epilogue: acc -> Cl[128 px][128 cols] bf16 (32KB, aliases Bl) -> 256B full-line stores
        unsigned short* Cl = &Bl[0];
        __syncthreads();
#pragma unroll
        for (int j = 0; j < 8; ++j) {
            float bs = (j < 4) ? bias[bn * 64 + j * 16 + lrow]
                               : bias[(bn + 4) * 64 + (j - 4) * 16 + lrow];
#pragma unroll
            for (int i = 0; i < 2; ++i)
#pragma unroll
                for (int jj = 0; jj < 4; ++jj)
                    Cl[(w * 32 + i * 16 + lk * 4 + jj) * 128 + j * 16 + lrow] =
                        f2bf(acc[i][j][jj] + bs);
        }
        __syncthreads();
        // dst chunk d (16 per px, 8 shorts each): [h0K(0-3) h0V(4-7) h1K(8-11) h1V(12-15)]
        // src chunk s in Cl: [K0(0-3) K1(4-7) V0(8-11) V1(12-15)]
#pragma unroll
        for (int it = 0; it < 8; ++it) {
            int idx = it * 256 + tid;
            int px = idx >> 4, d = idx & 15;
            int s = (d < 4) ? d : (d < 8) ? d + 4 : (d < 12) ? d - 4 : d;
            *(f32x4*)(C + (size_t)(chunk * 128 + px) * 512 + bn * 128 + d * 8) =
                *(const f32x4*)&Cl[px * 128 + s * 8];
        }
    } else {
        // Foff epilogue: fp32 direct stores (no bias); only K-slab accs are meaningful
#pragma unroll
        for (int i = 0; i < 2; ++i)
#pragma unroll
            for (int j = 0; j < 4; ++j)
#pragma unroll
                for (int jj = 0; jj < 4; ++jj) {
                    int m = chunk * 128 + w * 32 + i * 16 + lk * 4 + jj;
                    Foff[(size_t)m * 64 + j * 16 + lrow] = acc[i][j][jj];
                }
    }
}

// ---------------- split-bf16 MFMA GEMM (fp32 A/B in): C = A@B^T + bias ----------------
template <bool SPLIT, bool C_BF16>
__global__ __launch_bounds__(256) void gemm_bf16(
    const float* __restrict__ A, long long aBatch,
    const float* __restrict__ B, const float* __restrict__ bias,
    void* __restrict__ Cv, long long cBatch,
    int M, int N, int K, int lda) {
    __shared__ __align__(16) unsigned short Ah[64][40];
    __shared__ __align__(16) unsigned short Bh[64][40];
    __shared__ __align__(16) unsigned short Al[(SPLIT ? 64 : 1)][40];
    __shared__ __align__(16) unsigned short Bl[(SPLIT ? 64 : 1)][40];

    const int tid = threadIdx.x;
    const int m0 = blockIdx.x * 64, n0 = blockIdx.y * 64;
    const int batch = blockIdx.z;
    const float* Ab = A + (size_t)batch * aBatch;
    const int lane = tid & 63, wave = tid >> 6;
    const int wr = wave & 1, wc = wave >> 1;
    const int lrow = lane & 15, lk = lane >> 4;

    f32x4 acc[2][2] = {};

    for (int kt = 0; kt < K; kt += 32) {
        if (kt) __syncthreads();
        {
            int c4 = (tid & 7) * 4;
#pragma unroll
            for (int rep = 0; rep < 2; rep++) {
                int r = (tid >> 3) + rep * 32;
                int m = m0 + r; if (m >= M) m = M - 1;
                f32x4 v = *(const f32x4*)(Ab + (size_t)m * lda + kt + c4);
#pragma unroll
                for (int q = 0; q < 4; q++) {
                    unsigned short h = f2bf(v[q]);
                    Ah[r][c4 + q] = h;
                    if (SPLIT) Al[r][c4 + q] = f2bf(v[q] - bf2f(h));
                }
            }
        }
        {
            int c4 = (tid & 7) * 4;
#pragma unroll
            for (int rep = 0; rep < 2; rep++) {
                int r = (tid >> 3) + rep * 32;
                f32x4 v = *(const f32x4*)(B + (size_t)(n0 + r) * K + kt + c4);
#pragma unroll
                for (int q = 0; q < 4; q++) {
                    unsigned short h = f2bf(v[q]);
                    Bh[r][c4 + q] = h;
                    if (SPLIT) Bl[r][c4 + q] = f2bf(v[q] - bf2f(h));
                }
            }
        }
        __syncthreads();

        bf16x8 a_h[2], b_h[2], a_l[2], b_l[2];
#pragma unroll
        for (int i = 0; i < 2; i++) {
            a_h[i] = *(const bf16x8*)&Ah[wr * 32 + i * 16 + lrow][lk * 8];
            b_h[i] = *(const bf16x8*)&Bh[wc * 32 + i * 16 + lrow][lk * 8];
            if (SPLIT) {
                a_l[i] = *(const bf16x8*)&Al[wr * 32 + i * 16 + lrow][lk * 8];
                b_l[i] = *(const bf16x8*)&Bl[wc * 32 + i * 16 + lrow][lk * 8];
            }
        }
#pragma unroll
        for (int i = 0; i < 2; i++)
#pragma unroll
            for (int j = 0; j < 2; j++) {
                acc[i][j] = __builtin_amdgcn_mfma_f32_16x16x32_bf16(a_h[i], b_h[j], acc[i][j], 0, 0, 0);
                if (SPLIT) {
                    acc[i][j] = __builtin_amdgcn_mfma_f32_16x16x32_bf16(a_h[i], b_l[j], acc[i][j], 0, 0, 0);
                    acc[i][j] = __builtin_amdgcn_mfma_f32_16x16x32_bf16(a_l[i], b_h[j], acc[i][j], 0, 0, 0);
                }
            }
    }

#pragma unroll
    for (int i = 0; i < 2; i++)
#pragma unroll
        for (int j = 0; j < 2; j++) {
            int n = n0 + wc * 32 + j * 16 + lrow;
            float bs = bias[n];
#pragma unroll
            for (int jj = 0; jj < 4; jj++) {
                int m = m0 + wr * 32 + i * 16 + lk * 4 + jj;
                if (m < M) {
                    float val = acc[i][j][jj] + bs;
                    if (C_BF16)
                        ((unsigned short*)Cv)[(size_t)batch * cBatch + (size_t)m * N + n] = f2bf(val);
                    else
                        ((float*)Cv)[(size_t)batch * cBatch + (size_t)m * N + n] = val;
                }
            }
        }
}

// ---------------- fused deformable attention (projection + offsets fused in) ----------------
__global__ __launch_bounds__(512) void attn_kernel(
    const float* __restrict__ qcat, const float* __restrict__ points,
    const float* __restrict__ camM, const float* __restrict__ camb,
    const float* __restrict__ Foff, const unsigned short* __restrict__ kv_t,
    float* __restrict__ S) {
    int bk = blockIdx.x;            // b*900 + k
    int b = bk / 900, k = bk % 900;
    int h = threadIdx.x >> 6;       // wave = head
    int lane = threadIdx.x & 63;

    __shared__ __align__(16) float        ldsW[8][24][4];
    __shared__ __align__(16) unsigned int ldsI[8][24][4];
    __shared__ float ldsL[8][24];

    if (lane < 24) {
        int cam = lane >> 2, p = lane & 3;
        float pt0 = points[(size_t)bk * 3 + 0];
        float pt1 = points[(size_t)bk * 3 + 1];
        float pt2 = points[(size_t)bk * 3 + 2];
        const float* M = camM + cam * 6;
        float s0 = M[0] * pt0 + M[1] * pt1 + M[2] * pt2 + camb[cam * 2 + 0];
        float s1 = M[3] * pt0 + M[4] * pt1 + M[5] * pt2 + camb[cam * 2 + 1];
        float px0 = (1.f / (1.f + expf(-s0))) * 32.f;
        float px1 = (1.f / (1.f + expf(-s1))) * 88.f;
        {
            float gxb = 2.f * px0 / 32.f - 1.f, gyb = 2.f * px1 / 88.f - 1.f;
            float ixb = (gxb + 1.f) * 0.5f * 87.f;
            float iyb = (gyb + 1.f) * 0.5f * 31.f;
            float xb0 = floorf(ixb), yb0 = floorf(iyb), xb1 = xb0 + 1.f, yb1 = yb0 + 1.f;
            float wxb1 = ixb - xb0, wxb0 = xb1 - ixb, wyb1 = iyb - yb0, wyb0 = yb1 - iyb;
            float mb00 = (xb0 >= 0.f && xb0 <= 87.f && yb0 >= 0.f && yb0 <= 31.f) ? 1.f : 0.f;
            float mb01 = (xb1 >= 0.f && xb1 <= 87.f && yb0 >= 0.f && yb0 <= 31.f) ? 1.f : 0.f;
            float mb10 = (xb0 >= 0.f && xb0 <= 87.f && yb1 >= 0.f && yb1 <= 31.f) ? 1.f : 0.f;
            float mb11 = (xb1 >= 0.f && xb1 <= 87.f && yb1 >= 0.f && yb1 <= 31.f) ? 1.f : 0.f;
            float wb00 = wxb0 * wyb0 * mb00, wb01 = wxb1 * wyb0 * mb01;
            float wb10 = wxb0 * wyb1 * mb10, wb11 = wxb1 * wyb1 * mb11;
            int xib0 = (int)fminf(fmaxf(xb0, 0.f), 87.f);
            int xib1 = (int)fminf(fmaxf(xb1, 0.f), 87.f);
            int yib0 = (int)fminf(fmaxf(yb0, 0.f), 31.f);
            int yib1 = (int)fminf(fmaxf(yb1, 0.f), 31.f);
            size_t base = (size_t)(cam * 8 + b) * 2816;
            const float* f00 = Foff + (base + yib0 * 88 + xib0) * 64;
            const float* f01 = Foff + (base + yib0 * 88 + xib1) * 64;
            const float* f10 = Foff + (base + yib1 * 88 + xib0) * 64;
            const float* f11 = Foff + (base + yib1 * 88 + xib1) * 64;
            int j0 = (h * 4 + p) * 2;
            float o0 = qcat[(size_t)bk * 320 + 256 + j0]
                     + wb00 * f00[j0] + wb01 * f01[j0] + wb10 * f10[j0] + wb11 * f11[j0];
            float o1 = qcat[(size_t)bk * 320 + 256 + j0 + 1]
                     + wb00 * f00[j0 + 1] + wb01 * f01[j0 + 1] + wb10 * f10[j0 + 1] + wb11 * f11[j0 + 1];
            float pc0 = px0 + o0 * (1.f / 32.f);
            float pc1 = px1 + o1 * (1.f / 88.f);
            float gx = 2.f * (pc0 * (1.f / 32.f)) - 1.f;
            float gy = 2.f * (pc1 * (1.f / 88.f)) - 1.f;
            float ix = (gx + 1.f) * 0.5f * 87.f;
            float iy = (gy + 1.f) * 0.5f * 31.f;
            float x0 = floorf(ix), y0 = floorf(iy), x1 = x0 + 1.f, y1 = y0 + 1.f;
            float wx1 = ix - x0, wx0 = x1 - ix, wy1 = iy - y0, wy0 = y1 - iy;
            float m00 = (x0 >= 0.f && x0 <= 87.f && y0 >= 0.f && y0 <= 31.f) ? 1.f : 0.f;
            float m01 = (x1 >= 0.f && x1 <= 87.f && y0 >= 0.f && y0 <= 31.f) ? 1.f : 0.f;
            float m10 = (x0 >= 0.f && x0 <= 87.f && y1 >= 0.f && y1 <= 31.f) ? 1.f : 0.f;
            float m11 = (x1 >= 0.f && x1 <= 87.f && y1 >= 0.f && y1 <= 31.f) ? 1.f : 0.f;
            int xi0 = (int)fminf(fmaxf(x0, 0.f), 87.f);
            int xi1 = (int)fminf(fmaxf(x1, 0.f), 87.f);
            int yi0 = (int)fminf(fmaxf(y0, 0.f), 31.f);
            int yi1 = (int)fminf(fmaxf(y1, 0.f), 31.f);
            unsigned int img = (unsigned int)(cam * 8 + b) * 2816u;
            ldsW[h][lane][0] = wx0 * wy0 * m00;
            ldsW[h][lane][1] = wx1 * wy0 * m01;
            ldsW[h][lane][2] = wx0 * wy1 * m10;
            ldsW[h][lane][3] = wx1 * wy1 * m11;
            ldsI[h][lane][0] = (img + yi0 * 88 + xi0) * 1024u;
            ldsI[h][lane][1] = (img + yi0 * 88 + xi1) * 1024u;
            ldsI[h][lane][2] = (img + yi1 * 88 + xi0) * 1024u;
            ldsI[h][lane][3] = (img + yi1 * 88 + xi1) * 1024u;
        }
    }
    __syncthreads();

    const int p8 = lane >> 3, dlane = lane & 7;
    const int chB = h * 128 + dlane * 16;    // byte offset within pixel row
    const char* kvb = (const char*)kv_t;

    f32x4 qa = *(const f32x4*)(qcat + (size_t)bk * 320 + h * 32 + (dlane & 3) * 8);
    f32x4 qb = *(const f32x4*)(qcat + (size_t)bk * 320 + h * 32 + (dlane & 3) * 8 + 4);

    float vr[3][8];
    const float inv_sqrt = 0.17677669529663687f;
#pragma unroll
    for (int it = 0; it < 3; ++it) {
        int l = it * 8 + p8;
        f32x4 w = *(const f32x4*)ldsW[h][l];
        unsigned int i0 = ldsI[h][l][0], i1 = ldsI[h][l][1];
        unsigned int i2 = ldsI[h][l][2], i3 = ldsI[h][l][3];
        u32x4 u0 = *(const u32x4*)(kvb + i0 + chB);
        u32x4 u1 = *(const u32x4*)(kvb + i1 + chB);
        u32x4 u2 = *(const u32x4*)(kvb + i2 + chB);
        u32x4 u3 = *(const u32x4*)(kvb + i3 + chB);
#pragma unroll
        for (int q = 0; q < 4; ++q) {
            vr[it][2 * q] = w[0] * u2f(u0[q] << 16) + w[1] * u2f(u1[q] << 16)
                          + w[2] * u2f(u2[q] << 16) + w[3] * u2f(u3[q] << 16);
            vr[it][2 * q + 1] = w[0] * u2f(u0[q] & 0xFFFF0000u) + w[1] * u2f(u1[q] & 0xFFFF0000u)
                              + w[2] * u2f(u2[q] & 0xFFFF0000u) + w[3] * u2f(u3[q] & 0xFFFF0000u);
        }
        float t = qa[0] * vr[it][0] + qa[1] * vr[it][1] + qa[2] * vr[it][2] + qa[3] * vr[it][3]
                + qb[0] * vr[it][4] + qb[1] * vr[it][5] + qb[2] * vr[it][6] + qb[3] * vr[it][7];
        t += __shfl_xor(t, 1);
        t += __shfl_xor(t, 2);
        if (dlane == 0) ldsL[h][l] = t * inv_sqrt;
    }
    __syncthreads();

    float mx = -1e30f;
#pragma unroll
    for (int l = 0; l < 24; l++) mx = fmaxf(mx, ldsL[h][l]);
    float ssum = 0.f;
    float at3[3];
#pragma unroll
    for (int l = 0; l < 24; l++) {
        float e = __expf(ldsL[h][l] - mx);
        ssum += e;
        if ((l & 7) == p8) at3[l >> 3] = e;
    }
    float inv = 1.f / ssum;

    float o[8];
#pragma unroll
    for (int j = 0; j < 8; ++j)
        o[j] = at3[0] * vr[0][j] + at3[1] * vr[1][j] + at3[2] * vr[2][j];
#pragma unroll
    for (int j = 0; j < 8; ++j) {
        o[j] += __shfl_xor(o[j], 8);
        o[j] += __shfl_xor(o[j], 16);
        o[j] += __shfl_xor(o[j], 32);
    }
    if (p8 == 0 && dlane >= 4) {
        int d0 = (dlane - 4) * 8;
        f32x4 v0, v1;
        v0[0] = o[0] * inv; v0[1] = o[1] * inv; v0[2] = o[2] * inv; v0[3] = o[3] * inv;
        v1[0] = o[4] * inv; v1[1] = o[5] * inv; v1[2] = o[6] * inv; v1[3] = o[7] * inv;
        float* dst = &S[(size_t)b * 230400 + (size_t)h * 28800 + k * 32 + d0];
        *(f32x4*)dst = v0;
        *(f32x4*)(dst + 4) = v1;
    }
}

extern "C" void kernel_launch(void* const* d_in, const int* in_sizes, int n_in,
                              void* d_out, int out_size, void* d_ws, size_t ws_size,
                              hipStream_t stream) {
    const float* query    = (const float*)d_in[0];
    const float* points   = (const float*)d_in[1];
    const float* features = (const float*)d_in[2];
    const float* camM     = (const float*)d_in[3];
    const float* camb     = (const float*)d_in[4];
    const float* W_off    = (const float*)d_in[5];
    const float* b_off    = (const float*)d_in[6];
    const float* W_q      = (const float*)d_in[7];
    const float* b_q      = (const float*)d_in[8];
    const float* W_k      = (const float*)d_in[9];
    const float* b_k      = (const float*)d_in[10];
    const float* W_v      = (const float*)d_in[11];
    const float* b_v      = (const float*)d_in[12];
    const float* W_o      = (const float*)d_in[13];
    const float* b_o      = (const float*)d_in[14];

    char* ws = (char*)d_ws;
    unsigned short* feat_t = (unsigned short*)ws; ws += 69206016;   // blocked [1056][8][128][32] bf16
    unsigned short* kv_t   = (unsigned short*)ws; ws += 138412032;  // [135168][8 heads][64] bf16
    float* Foff   = (float*)ws; ws += 34603008;                     // [135168][64]
    float* qcat   = (float*)ws; ws += 9216000;                      // [7200][320] = [q_proj | qWoff]
    float* S      = (float*)ws; ws += 7372800;                      // [8][230400] scrambled
    unsigned short* Wkv = (unsigned short*)ws; ws += 524288;        // blocked [4][8][128][32] bf16
    float* bkv    = (float*)ws; ws += 2048;                         // [512]
    unsigned short* Woffp = (unsigned short*)ws; ws += 65536;       // blocked [8 kt][4096] bf16
    float* Wcat   = (float*)ws; ws += 327680;                       // [320][256] fp32
    float* bcat   = (float*)ws; ws += 1280;                         // [320]

    prep_all<<<512, 256, 0, stream>>>(W_k, b_k, W_v, b_v, W_q, b_q, W_off, b_off,
                                      Wkv, bkv, Woffp, Wcat, bcat);
    transpose_feat<<<dim3(88, 8, 48), 256, 0, stream>>>(features, feat_t);
    // kv_t (bn 0-3, K+V paired full-line stores) + Foff (bn 4)
    gemm_kv2<<<5280, 256, 0, stream>>>(feat_t, Wkv, Woffp, bkv, kv_t, Foff);
    // qcat = query @ [W_q|W_off]^T + [b_q|b_off] : [7200 x 320]
    gemm_bf16<true, false><<<dim3(113, 5, 1), 256, 0, stream>>>(
        query, 0, Wcat, bcat, qcat, 0, 7200, 320, 256, 256);
    // attention (projection + offset sampling fused in)
    attn_kernel<<<7200, 512, 0, stream>>>(qcat, points, camM, camb, Foff, kv_t, S);
    // out = S @ W_o^T + b_o : [7200 x 256]
    gemm_bf16<true, false><<<dim3(113, 4, 1), 256, 0, stream>>>(
        S, 0, W_o, b_o, d_out, 0, 7200, 256, 256, 256);
}

// Round 22
// 219.882 us; speedup vs baseline: 1.0747x; 1.0644x over previous
//
#include <hip/hip_runtime.h>

typedef __attribute__((ext_vector_type(4))) float f32x4;
typedef __attribute__((ext_vector_type(8))) short bf16x8;
typedef __attribute__((ext_vector_type(4))) unsigned int u32x4;

__device__ __forceinline__ unsigned short f2bf(float f) {
    union { float f; unsigned int u; } x; x.f = f;
    unsigned int u = x.u;
    return (unsigned short)((u + 0x7FFFu + ((u >> 16) & 1u)) >> 16);
}
__device__ __forceinline__ float bf2f(unsigned short b) {
    union { unsigned int u; float f; } x; x.u = ((unsigned int)b) << 16;
    return x.f;
}
__device__ __forceinline__ float u2f(unsigned int u) {
    union { unsigned int u; float f; } x; x.u = u; return x.f;
}

// feat_t blocked layout (row r, ch k): ((r>>7)*8 + (k>>5))*4096 + (r&127)*32 + (k&31)
// LDS staging swizzle: pre-swizzled GLOBAL source (lsw), reads use chunk lk ^ ((lrow>>1)&3).
// kv_t layout: [pixel][head][K ch 0-31 | V ch 0-31] bf16 (128B per head, interleaved).
// Wall: [72 slabs = 9 units x 8 kt][64 rows][32 ch] bf16. Unit u<8: rows 0-31 = W_k[u*32..],
// rows 32-63 = W_v[u*32..]; unit 8 = W_off rows 0-63. ball[9][64] matching bias (unit 8 = 0).

// ---------------- prep (merged): Wall bf16, ball, Wcat=[Wq|Woff] fp32 ----------------
__global__ void prep_all(const float* __restrict__ Wk, const float* __restrict__ bk,
                         const float* __restrict__ Wv, const float* __restrict__ bv,
                         const float* __restrict__ Wq, const float* __restrict__ bq,
                         const float* __restrict__ Woff, const float* __restrict__ boff,
                         unsigned short* __restrict__ Wall, float* __restrict__ ball,
                         float* __restrict__ Wcat, float* __restrict__ bcat) {
    int i = blockIdx.x * 256 + threadIdx.x;   // grid 576*256 = 147456
    {
        int slab = i >> 11, r = (i >> 5) & 63, c = i & 31;
        int u = slab >> 3, kt = slab & 7;
        float v;
        if (u < 8) v = (r < 32) ? Wk[(u * 32 + r) * 256 + kt * 32 + c]
                                : Wv[(u * 32 + r - 32) * 256 + kt * 32 + c];
        else       v = Woff[r * 256 + kt * 32 + c];
        Wall[i] = f2bf(v);
    }
    if (i < 576) {
        int u = i >> 6, r = i & 63;
        ball[i] = (u < 8) ? ((r < 32) ? bk[u * 32 + r] : bv[u * 32 + r - 32]) : 0.f;
    }
    if (i < 320 * 256) Wcat[i] = (i < 65536) ? Wq[i] : Woff[i - 65536];
    if (i < 320) bcat[i] = (i < 256) ? bq[i] : boff[i - 256];
}

// ---------------- transpose features [48][256][2816] -> bf16 blocked ----------------
__global__ __launch_bounds__(256) void transpose_feat(const float* __restrict__ src,
                                                      unsigned short* __restrict__ dst) {
    __shared__ float tile[32][33];
    int img = blockIdx.z;
    int p0 = blockIdx.x * 32;   // pixel
    int d0 = blockIdx.y * 32;   // channel
    int tx = threadIdx.x & 31, ty = threadIdx.x >> 5;
    const float* s = src + (size_t)img * 256 * 2816;
#pragma unroll
    for (int i = 0; i < 4; i++) tile[ty + 8 * i][tx] = s[(size_t)(d0 + ty + 8 * i) * 2816 + p0 + tx];
    __syncthreads();
    int m = img * 2816 + p0;
    unsigned short* o = dst + ((size_t)(m >> 7) * 8 + (d0 >> 5)) * 4096 + (m & 127) * 32;
#pragma unroll
    for (int i = 0; i < 4; i++) o[(ty + 8 * i) * 32 + tx] = f2bf(tile[tx][ty + 8 * i]);
}

// ---------------- fused kv+off projection: resident-A, wave-private B, zero-barrier K-loop ----
// Block = 64 px x 576 cols (9 units x 64). A (64px x 256ch bf16, 32KB) staged once.
// Wave w owns cols w*16..w*16+16 of each unit. B slab per (unit,kt) per wave = 1KB,
// ring 4 slots, depth-3 prefetch, per-wave s_waitcnt vmcnt(N). LDS 48KB -> 3 blocks/CU.
// Unit u<8 -> kv_t cols u*64..+64 (full 128B line/px); unit 8 -> Foff fp32.
__global__ __launch_bounds__(256) void gemm_fused(
    const unsigned short* __restrict__ A,
    const unsigned short* __restrict__ Wall,
    const float* __restrict__ ball,
    unsigned short* __restrict__ C,
    float* __restrict__ Foff) {
    __shared__ __align__(16) unsigned short Alds[16384];  // 32KB: [8 kt][64 px][32 ch] (swizzled)
    __shared__ __align__(16) unsigned short Bring[8192];  // 16KB: [4 slots][4 waves][16 r][32 ch]

    const int tid = threadIdx.x, lane = tid & 63, w = tid >> 6;
    const int lrow = lane & 15, lk = lane >> 4;
    const int lsw = (lane >> 2) * 32 + (((lane & 3) ^ ((lane >> 3) & 3)) * 8);
    const int ckx = ((lrow >> 1) & 3);    // read-side chunk xor
    const int bid = blockIdx.x;
    const int wgid = (bid & 7) * 264 + (bid >> 3);   // XCD swizzle (2112 = 8*264)
    // 64-px half-chunk: feat chunk = wgid>>1, half = wgid&1
    const unsigned short* A0 = A + (size_t)(wgid >> 1) * 32768 + (wgid & 1) * 2048;

    // ---- stage A (once): wave w stages kt = 2w, 2w+1; 4 x 1KB each ----
#pragma unroll
    for (int kk = 0; kk < 2; ++kk) {
        int kt = w * 2 + kk;
#pragma unroll
        for (int i = 0; i < 4; ++i) {
            __builtin_amdgcn_global_load_lds(
                (const __attribute__((address_space(1))) unsigned int*)(A0 + kt * 4096 + i * 512 + lsw),
                (__attribute__((address_space(3))) unsigned int*)&Alds[kt * 2048 + i * 512], 16, 0, 0);
        }
    }

#define STAGE_B(S3)                                                                          \
    __builtin_amdgcn_global_load_lds(                                                        \
        (const __attribute__((address_space(1))) unsigned int*)(Wall + (S3) * 2048 + w * 512 + lsw), \
        (__attribute__((address_space(3))) unsigned int*)&Bring[((S3) & 3) * 2048 + w * 512], 16, 0, 0);

    STAGE_B(0) STAGE_B(1) STAGE_B(2)
    __syncthreads();   // drains everything: A resident, B slabs 0-2 resident

    f32x4 acc[4] = {};   // [i]: px = i*16 + lk*4 + jj, col_local = w*16 + lrow

    // COMP: wait B(S) landed -> ds_read bfr + af[4] -> drain own ds_reads ->
    // stage B(S+3) (slot (S+3)&3 = (S-1)&3, its reads long done) -> 4 MFMAs.
#define COMP_STEP(S, NW)                                                                     \
    {                                                                                        \
        asm volatile("s_waitcnt vmcnt(%0)" :: "i"(NW) : "memory");                           \
        bf16x8 bfr, af[4];                                                                   \
        bfr = *(const bf16x8*)&Bring[((S) & 3) * 2048 + w * 512 + lrow * 32 + (lk ^ ckx) * 8]; \
        _Pragma("unroll") for (int i = 0; i < 4; ++i)                                        \
            af[i] = *(const bf16x8*)&Alds[((S) & 7) * 2048 + (i * 16 + lrow) * 32 + (lk ^ ckx) * 8]; \
        if ((S) + 3 < 72) {                                                                  \
            asm volatile("s_waitcnt lgkmcnt(0)" ::: "memory");                               \
            STAGE_B((S) + 3)                                                                 \
        }                                                                                    \
        _Pragma("unroll") for (int i = 0; i < 4; ++i)                                        \
            acc[i] = __builtin_amdgcn_mfma_f32_16x16x32_bf16(af[i], bfr, acc[i], 0, 0, 0);   \
    }

#define EPI_KV(U)                                                                            \
    {                                                                                        \
        float bs = ball[(U) * 64 + w * 16 + lrow];                                           \
        _Pragma("unroll") for (int i = 0; i < 4; ++i) {                                      \
            _Pragma("unroll") for (int jj = 0; jj < 4; ++jj)                                 \
                C[(size_t)(wgid * 64 + i * 16 + lk * 4 + jj) * 512 + (U) * 64 + w * 16 + lrow] = \
                    f2bf(acc[i][jj] + bs);                                                   \
            acc[i] = (f32x4){0.f, 0.f, 0.f, 0.f};                                            \
        }                                                                                    \
    }

#define UNIT(U)                                                                              \
    COMP_STEP((U) * 8 + 0, 2) COMP_STEP((U) * 8 + 1, 2) COMP_STEP((U) * 8 + 2, 2)            \
    COMP_STEP((U) * 8 + 3, 2) COMP_STEP((U) * 8 + 4, 2) COMP_STEP((U) * 8 + 5, 2)            \
    COMP_STEP((U) * 8 + 6, 2) COMP_STEP((U) * 8 + 7, 2) EPI_KV(U)

    UNIT(0) UNIT(1) UNIT(2) UNIT(3) UNIT(4) UNIT(5) UNIT(6) UNIT(7)

    // unit 8 (Foff): steps 64..71, tail vmcnt 2/2/2/2/2/2/1/0
    COMP_STEP(64, 2) COMP_STEP(65, 2) COMP_STEP(66, 2) COMP_STEP(67, 2)
    COMP_STEP(68, 2) COMP_STEP(69, 2) COMP_STEP(70, 1) COMP_STEP(71, 0)
    {
#pragma unroll
        for (int i = 0; i < 4; ++i)
#pragma unroll
            for (int jj = 0; jj < 4; ++jj)
                Foff[(size_t)(wgid * 64 + i * 16 + lk * 4 + jj) * 64 + w * 16 + lrow] = acc[i][jj];
    }
#undef UNIT
#undef EPI_KV
#undef COMP_STEP
#undef STAGE_B
}

// ---------------- split-bf16 MFMA GEMM (fp32 A/B in): C = A@B^T + bias ----------------
template <bool SPLIT, bool C_BF16>
__global__ __launch_bounds__(256) void gemm_bf16(
    const float* __restrict__ A, long long aBatch,
    const float* __restrict__ B, const float* __restrict__ bias,
    void* __restrict__ Cv, long long cBatch,
    int M, int N, int K, int lda) {
    __shared__ __align__(16) unsigned short Ah[64][40];
    __shared__ __align__(16) unsigned short Bh[64][40];
    __shared__ __align__(16) unsigned short Al[(SPLIT ? 64 : 1)][40];
    __shared__ __align__(16) unsigned short Bl[(SPLIT ? 64 : 1)][40];

    const int tid = threadIdx.x;
    const int m0 = blockIdx.x * 64, n0 = blockIdx.y * 64;
    const int batch = blockIdx.z;
    const float* Ab = A + (size_t)batch * aBatch;
    const int lane = tid & 63, wave = tid >> 6;
    const int wr = wave & 1, wc = wave >> 1;
    const int lrow = lane & 15, lk = lane >> 4;

    f32x4 acc[2][2] = {};

    for (int kt = 0; kt < K; kt += 32) {
        if (kt) __syncthreads();
        {
            int c4 = (tid & 7) * 4;
#pragma unroll
            for (int rep = 0; rep < 2; rep++) {
                int r = (tid >> 3) + rep * 32;
                int m = m0 + r; if (m >= M) m = M - 1;
                f32x4 v = *(const f32x4*)(Ab + (size_t)m * lda + kt + c4);
#pragma unroll
                for (int q = 0; q < 4; q++) {
                    unsigned short h = f2bf(v[q]);
                    Ah[r][c4 + q] = h;
                    if (SPLIT) Al[r][c4 + q] = f2bf(v[q] - bf2f(h));
                }
            }
        }
        {
            int c4 = (tid & 7) * 4;
#pragma unroll
            for (int rep = 0; rep < 2; rep++) {
                int r = (tid >> 3) + rep * 32;
                f32x4 v = *(const f32x4*)(B + (size_t)(n0 + r) * K + kt + c4);
#pragma unroll
                for (int q = 0; q < 4; q++) {
                    unsigned short h = f2bf(v[q]);
                    Bh[r][c4 + q] = h;
                    if (SPLIT) Bl[r][c4 + q] = f2bf(v[q] - bf2f(h));
                }
            }
        }
        __syncthreads();

        bf16x8 a_h[2], b_h[2], a_l[2], b_l[2];
#pragma unroll
        for (int i = 0; i < 2; i++) {
            a_h[i] = *(const bf16x8*)&Ah[wr * 32 + i * 16 + lrow][lk * 8];
            b_h[i] = *(const bf16x8*)&Bh[wc * 32 + i * 16 + lrow][lk * 8];
            if (SPLIT) {
                a_l[i] = *(const bf16x8*)&Al[wr * 32 + i * 16 + lrow][lk * 8];
                b_l[i] = *(const bf16x8*)&Bl[wc * 32 + i * 16 + lrow][lk * 8];
            }
        }
#pragma unroll
        for (int i = 0; i < 2; i++)
#pragma unroll
            for (int j = 0; j < 2; j++) {
                acc[i][j] = __builtin_amdgcn_mfma_f32_16x16x32_bf16(a_h[i], b_h[j], acc[i][j], 0, 0, 0);
                if (SPLIT) {
                    acc[i][j] = __builtin_amdgcn_mfma_f32_16x16x32_bf16(a_h[i], b_l[j], acc[i][j], 0, 0, 0);
                    acc[i][j] = __builtin_amdgcn_mfma_f32_16x16x32_bf16(a_l[i], b_h[j], acc[i][j], 0, 0, 0);
                }
            }
    }

#pragma unroll
    for (int i = 0; i < 2; i++)
#pragma unroll
        for (int j = 0; j < 2; j++) {
            int n = n0 + wc * 32 + j * 16 + lrow;
            float bs = bias[n];
#pragma unroll
            for (int jj = 0; jj < 4; jj++) {
                int m = m0 + wr * 32 + i * 16 + lk * 4 + jj;
                if (m < M) {
                    float val = acc[i][j][jj] + bs;
                    if (C_BF16)
                        ((unsigned short*)Cv)[(size_t)batch * cBatch + (size_t)m * N + n] = f2bf(val);
                    else
                        ((float*)Cv)[(size_t)batch * cBatch + (size_t)m * N + n] = val;
                }
            }
        }
}

// ---------------- fused deformable attention (projection + offsets fused in) ----------------
__global__ __launch_bounds__(512) void attn_kernel(
    const float* __restrict__ qcat, const float* __restrict__ points,
    const float* __restrict__ camM, const float* __restrict__ camb,
    const float* __restrict__ Foff, const unsigned short* __restrict__ kv_t,
    float* __restrict__ S) {
    int bk = blockIdx.x;            // b*900 + k
    int b = bk / 900, k = bk % 900;
    int h = threadIdx.x >> 6;       // wave = head
    int lane = threadIdx.x & 63;

    __shared__ __align__(16) float        ldsW[8][24][4];
    __shared__ __align__(16) unsigned int ldsI[8][24][4];
    __shared__ float ldsL[8][24];

    if (lane < 24) {
        int cam = lane >> 2, p = lane & 3;
        float pt0 = points[(size_t)bk * 3 + 0];
        float pt1 = points[(size_t)bk * 3 + 1];
        float pt2 = points[(size_t)bk * 3 + 2];
        const float* M = camM + cam * 6;
        float s0 = M[0] * pt0 + M[1] * pt1 + M[2] * pt2 + camb[cam * 2 + 0];
        float s1 = M[3] * pt0 + M[4] * pt1 + M[5] * pt2 + camb[cam * 2 + 1];
        float px0 = (1.f / (1.f + expf(-s0))) * 32.f;
        float px1 = (1.f / (1.f + expf(-s1))) * 88.f;
        {
            float gxb = 2.f * px0 / 32.f - 1.f, gyb = 2.f * px1 / 88.f - 1.f;
            float ixb = (gxb + 1.f) * 0.5f * 87.f;
            float iyb = (gyb + 1.f) * 0.5f * 31.f;
            float xb0 = floorf(ixb), yb0 = floorf(iyb), xb1 = xb0 + 1.f, yb1 = yb0 + 1.f;
            float wxb1 = ixb - xb0, wxb0 = xb1 - ixb, wyb1 = iyb - yb0, wyb0 = yb1 - iyb;
            float mb00 = (xb0 >= 0.f && xb0 <= 87.f && yb0 >= 0.f && yb0 <= 31.f) ? 1.f : 0.f;
            float mb01 = (xb1 >= 0.f && xb1 <= 87.f && yb0 >= 0.f && yb0 <= 31.f) ? 1.f : 0.f;
            float mb10 = (xb0 >= 0.f && xb0 <= 87.f && yb1 >= 0.f && yb1 <= 31.f) ? 1.f : 0.f;
            float mb11 = (xb1 >= 0.f && xb1 <= 87.f && yb1 >= 0.f && yb1 <= 31.f) ? 1.f : 0.f;
            float wb00 = wxb0 * wyb0 * mb00, wb01 = wxb1 * wyb0 * mb01;
            float wb10 = wxb0 * wyb1 * mb10, wb11 = wxb1 * wyb1 * mb11;
            int xib0 = (int)fminf(fmaxf(xb0, 0.f), 87.f);
            int xib1 = (int)fminf(fmaxf(xb1, 0.f), 87.f);
            int yib0 = (int)fminf(fmaxf(yb0, 0.f), 31.f);
            int yib1 = (int)fminf(fmaxf(yb1, 0.f), 31.f);
            size_t base = (size_t)(cam * 8 + b) * 2816;
            const float* f00 = Foff + (base + yib0 * 88 + xib0) * 64;
            const float* f01 = Foff + (base + yib0 * 88 + xib1) * 64;
            const float* f10 = Foff + (base + yib1 * 88 + xib0) * 64;
            const float* f11 = Foff + (base + yib1 * 88 + xib1) * 64;
            int j0 = (h * 4 + p) * 2;
            float o0 = qcat[(size_t)bk * 320 + 256 + j0]
                     + wb00 * f00[j0] + wb01 * f01[j0] + wb10 * f10[j0] + wb11 * f11[j0];
            float o1 = qcat[(size_t)bk * 320 + 256 + j0 + 1]
                     + wb00 * f00[j0 + 1] + wb01 * f01[j0 + 1] + wb10 * f10[j0 + 1] + wb11 * f11[j0 + 1];
            float pc0 = px0 + o0 * (1.f / 32.f);
            float pc1 = px1 + o1 * (1.f / 88.f);
            float gx = 2.f * (pc0 * (1.f / 32.f)) - 1.f;
            float gy = 2.f * (pc1 * (1.f / 88.f)) - 1.f;
            float ix = (gx + 1.f) * 0.5f * 87.f;
            float iy = (gy + 1.f) * 0.5f * 31.f;
            float x0 = floorf(ix), y0 = floorf(iy), x1 = x0 + 1.f, y1 = y0 + 1.f;
            float wx1 = ix - x0, wx0 = x1 - ix, wy1 = iy - y0, wy0 = y1 - iy;
            float m00 = (x0 >= 0.f && x0 <= 87.f && y0 >= 0.f && y0 <= 31.f) ? 1.f : 0.f;
            float m01 = (x1 >= 0.f && x1 <= 87.f && y0 >= 0.f && y0 <= 31.f) ? 1.f : 0.f;
            float m10 = (x0 >= 0.f && x0 <= 87.f && y1 >= 0.f && y1 <= 31.f) ? 1.f : 0.f;
            float m11 = (x1 >= 0.f && x1 <= 87.f && y1 >= 0.f && y1 <= 31.f) ? 1.f : 0.f;
            int xi0 = (int)fminf(fmaxf(x0, 0.f), 87.f);
            int xi1 = (int)fminf(fmaxf(x1, 0.f), 87.f);
            int yi0 = (int)fminf(fmaxf(y0, 0.f), 31.f);
            int yi1 = (int)fminf(fmaxf(y1, 0.f), 31.f);
            unsigned int img = (unsigned int)(cam * 8 + b) * 2816u;
            ldsW[h][lane][0] = wx0 * wy0 * m00;
            ldsW[h][lane][1] = wx1 * wy0 * m01;
            ldsW[h][lane][2] = wx0 * wy1 * m10;
            ldsW[h][lane][3] = wx1 * wy1 * m11;
            ldsI[h][lane][0] = (img + yi0 * 88 + xi0) * 1024u;
            ldsI[h][lane][1] = (img + yi0 * 88 + xi1) * 1024u;
            ldsI[h][lane][2] = (img + yi1 * 88 + xi0) * 1024u;
            ldsI[h][lane][3] = (img + yi1 * 88 + xi1) * 1024u;
        }
    }
    __syncthreads();

    const int p8 = lane >> 3, dlane = lane & 7;
    const int chB = h * 128 + dlane * 16;    // byte offset within pixel row
    const char* kvb = (const char*)kv_t;

    f32x4 qa = *(const f32x4*)(qcat + (size_t)bk * 320 + h * 32 + (dlane & 3) * 8);
    f32x4 qb = *(const f32x4*)(qcat + (size_t)bk * 320 + h * 32 + (dlane & 3) * 8 + 4);

    float vr[3][8];
    const float inv_sqrt = 0.17677669529663687f;
#pragma unroll
    for (int it = 0; it < 3; ++it) {
        int l = it * 8 + p8;
        f32x4 w = *(const f32x4*)ldsW[h][l];
        unsigned int i0 = ldsI[h][l][0], i1 = ldsI[h][l][1];
        unsigned int i2 = ldsI[h][l][2], i3 = ldsI[h][l][3];
        u32x4 u0 = *(const u32x4*)(kvb + i0 + chB);
        u32x4 u1 = *(const u32x4*)(kvb + i1 + chB);
        u32x4 u2 = *(const u32x4*)(kvb + i2 + chB);
        u32x4 u3 = *(const u32x4*)(kvb + i3 + chB);
#pragma unroll
        for (int q = 0; q < 4; ++q) {
            vr[it][2 * q] = w[0] * u2f(u0[q] << 16) + w[1] * u2f(u1[q] << 16)
                          + w[2] * u2f(u2[q] << 16) + w[3] * u2f(u3[q] << 16);
            vr[it][2 * q + 1] = w[0] * u2f(u0[q] & 0xFFFF0000u) + w[1] * u2f(u1[q] & 0xFFFF0000u)
                              + w[2] * u2f(u2[q] & 0xFFFF0000u) + w[3] * u2f(u3[q] & 0xFFFF0000u);
        }
        float t = qa[0] * vr[it][0] + qa[1] * vr[it][1] + qa[2] * vr[it][2] + qa[3] * vr[it][3]
                + qb[0] * vr[it][4] + qb[1] * vr[it][5] + qb[2] * vr[it][6] + qb[3] * vr[it][7];
        t += __shfl_xor(t, 1);
        t += __shfl_xor(t, 2);
        if (dlane == 0) ldsL[h][l] = t * inv_sqrt;
    }
    __syncthreads();

    float mx = -1e30f;
#pragma unroll
    for (int l = 0; l < 24; l++) mx = fmaxf(mx, ldsL[h][l]);
    float ssum = 0.f;
    float at3[3];
#pragma unroll
    for (int l = 0; l < 24; l++) {
        float e = __expf(ldsL[h][l] - mx);
        ssum += e;
        if ((l & 7) == p8) at3[l >> 3] = e;
    }
    float inv = 1.f / ssum;

    float o[8];
#pragma unroll
    for (int j = 0; j < 8; ++j)
        o[j] = at3[0] * vr[0][j] + at3[1] * vr[1][j] + at3[2] * vr[2][j];
#pragma unroll
    for (int j = 0; j < 8; ++j) {
        o[j] += __shfl_xor(o[j], 8);
        o[j] += __shfl_xor(o[j], 16);
        o[j] += __shfl_xor(o[j], 32);
    }
    if (p8 == 0 && dlane >= 4) {
        int d0 = (dlane - 4) * 8;
        f32x4 v0, v1;
        v0[0] = o[0] * inv; v0[1] = o[1] * inv; v0[2] = o[2] * inv; v0[3] = o[3] * inv;
        v1[0] = o[4] * inv; v1[1] = o[5] * inv; v1[2] = o[6] * inv; v1[3] = o[7] * inv;
        float* dst = &S[(size_t)b * 230400 + (size_t)h * 28800 + k * 32 + d0];
        *(f32x4*)dst = v0;
        *(f32x4*)(dst + 4) = v1;
    }
}

extern "C" void kernel_launch(void* const* d_in, const int* in_sizes, int n_in,
                              void* d_out, int out_size, void* d_ws, size_t ws_size,
                              hipStream_t stream) {
    const float* query    = (const float*)d_in[0];
    const float* points   = (const float*)d_in[1];
    const float* features = (const float*)d_in[2];
    const float* camM     = (const float*)d_in[3];
    const float* camb     = (const float*)d_in[4];
    const float* W_off    = (const float*)d_in[5];
    const float* b_off    = (const float*)d_in[6];
    const float* W_q      = (const float*)d_in[7];
    const float* b_q      = (const float*)d_in[8];
    const float* W_k      = (const float*)d_in[9];
    const float* b_k      = (const float*)d_in[10];
    const float* W_v      = (const float*)d_in[11];
    const float* b_v      = (const float*)d_in[12];
    const float* W_o      = (const float*)d_in[13];
    const float* b_o      = (const float*)d_in[14];

    char* ws = (char*)d_ws;
    unsigned short* feat_t = (unsigned short*)ws; ws += 69206016;   // blocked [1056][8][128][32] bf16
    unsigned short* kv_t   = (unsigned short*)ws; ws += 138412032;  // [135168][8 heads][64] bf16
    float* Foff   = (float*)ws; ws += 34603008;                     // [135168][64]
    float* qcat   = (float*)ws; ws += 9216000;                      // [7200][320] = [q_proj | qWoff]
    float* S      = (float*)ws; ws += 7372800;                      // [8][230400] scrambled
    unsigned short* Wall = (unsigned short*)ws; ws += 294912;       // [72][2048] bf16
    float* ball   = (float*)ws; ws += 4096;                         // [9][64] (padded)
    float* Wcat   = (float*)ws; ws += 327680;                       // [320][256] fp32
    float* bcat   = (float*)ws; ws += 1280;                         // [320]

    prep_all<<<576, 256, 0, stream>>>(W_k, b_k, W_v, b_v, W_q, b_q, W_off, b_off,
                                      Wall, ball, Wcat, bcat);
    transpose_feat<<<dim3(88, 8, 48), 256, 0, stream>>>(features, feat_t);
    // kv_t (units 0-7, full-line writes) + Foff (unit 8): resident-A zero-barrier pipeline
    gemm_fused<<<2112, 256, 0, stream>>>(feat_t, Wall, ball, kv_t, Foff);
    // qcat = query @ [W_q|W_off]^T + [b_q|b_off] : [7200 x 320]
    gemm_bf16<true, false><<<dim3(113, 5, 1), 256, 0, stream>>>(
        query, 0, Wcat, bcat, qcat, 0, 7200, 320, 256, 256);
    // attention (projection + offset sampling fused in)
    attn_kernel<<<7200, 512, 0, stream>>>(qcat, points, camM, camb, Foff, kv_t, S);
    // out = S @ W_o^T + b_o : [7200 x 256]
    gemm_bf16<true, false><<<dim3(113, 4, 1), 256, 0, stream>>>(
        S, 0, W_o, b_o, d_out, 0, 7200, 256, 256, 256);
}